// Round 16
// baseline (113.318 us; speedup 1.0000x reference)
//
#include <hip/hip_runtime.h>
#include <hip/hip_bf16.h>
#include <math.h>

typedef __attribute__((ext_vector_type(8))) _Float16 half8;
typedef __attribute__((ext_vector_type(4))) _Float16 half4;
typedef __attribute__((ext_vector_type(4))) float f32x4;

#define EMBD 128
#define H1 256
#define H2 128
#define SLEN 50
#define NROWS 4096
#define MTILE 32
#define DENSE_GRID 1024

// ---- d_ws layout (bytes) ----
#define WS_FRAGS    0          // half8 frags[8192]  (131072)
#define WS_CNT      131072     // int counter (pad to 131200)
#define WS_ROWSTART 131200     // int rowstart[4096] (16384) -> 147584
#define WS_PACKED   147584     // u32 packed[204800] (819200) -> 966784
#define WS_PARTIAL  966784     // float partial[4096][3][128] (6291456) — NO init needed

// Branch-free GELU, exact-erf form via Abramowitz-Stegun 7.1.26 (|err|<=1.5e-7).
__device__ __forceinline__ float gelu_exact(float h) {
    float ah = fabsf(h);
    float d  = fmaf(0.23163845f, ah, 1.0f);
    float t;
    asm("v_rcp_f32 %0, %1" : "=v"(t) : "v"(d));
    float p = fmaf(1.061405429f, t, -1.453152027f);
    p = fmaf(p, t, 1.421413741f);
    p = fmaf(p, t, -0.284496736f);
    p = fmaf(p, t, 0.254829592f);
    p = p * t;
    float e;                                   // v_exp_f32 computes 2^x
    float x2 = h * h * -0.72134752f;           // -h^2/2 * log2(e)
    asm("v_exp_f32 %0, %1" : "=v"(e) : "v"(x2));
    float er = fmaf(-p, e, 1.0f);
    return fmaf(0.5f * ah, er, 0.5f * h);
}

// LDS-only barrier (no vmcnt drain): in-flight global loads survive it.
#define BARRIER_LDS() asm volatile("s_waitcnt lgkmcnt(0)\n\ts_barrier" ::: "memory")

// ---------------------------------------------------------------------------
// K0 (fused setup, 512 threads):
//   blocks 0..15   : w1/w2 fp32 -> fp16 MFMA fragments (8-wave layout, proven)
//   blocks 16..527 : wave-parallel compaction — one ROW per wave, lane t
//                    writes token t (coalesced); rowstart[r] stashed for head.
// cnt zeroed beforehand via hipMemsetAsync.
// ---------------------------------------------------------------------------
__global__ __launch_bounds__(512) void setup_kernel(
    const float* __restrict__ w1, const float* __restrict__ w2,
    const int* __restrict__ ids, const int* __restrict__ lens,
    half8* __restrict__ frags, unsigned* __restrict__ packed,
    int* __restrict__ cnt, int* __restrict__ rowstart)
{
    int b = blockIdx.x, t = threadIdx.x;
    if (b < 16) {
        int f = b * 512 + t;   // 0..8191
        half8 v;
        if (f < 4096) {
            int fragid = f >> 6, lane = f & 63;
            int kt = fragid >> 4, nt = fragid & 15;
            int col = nt * 16 + (lane & 15);
            int kb  = kt * 32 + (lane >> 4) * 8;
            #pragma unroll
            for (int i = 0; i < 8; ++i) v[i] = (_Float16)w1[(size_t)(kb + i) * H1 + col];
            frags[f] = v;
        } else {
            int f2 = f - 4096;
            int fragid = f2 >> 6, lane = f2 & 63;
            int kt = fragid >> 3, ntc = fragid & 7;
            int col = ntc * 16 + (lane & 15);
            int kb  = kt * 32 + (lane >> 4) * 8;
            #pragma unroll
            for (int i = 0; i < 8; ++i) v[i] = (_Float16)w2[(size_t)(kb + i) * H2 + col];
            frags[4096 + f2] = v;
        }
    } else {
        // ---- compaction: row per wave, token per lane ----
        int r    = (b - 16) * 8 + (t >> 6);   // 0..4095
        int lane = t & 63;
        int len = lens[r]; len = len < 1 ? 1 : (len > SLEN ? SLEN : len);
        int base;
        if (lane == 0) base = atomicAdd(cnt, len);
        base = __shfl(base, 0, 64);
        if (lane == 0) rowstart[r] = base;
        if (lane < len)
            packed[base + lane] = (unsigned)ids[r * SLEN + lane] | ((unsigned)r << 17);
    }
}

// ---------------------------------------------------------------------------
// K1: dense 32-token tiles, 512 threads (8 waves). BYTE-IDENTICAL to the
//     proven R15 dense kernel (54.6us, absmax 0.015625). Weights in registers
//     at 8-way N-split; wave w: GEMM1 cols [w*32,+32), GEMM2 cols [w*16,+16).
// ---------------------------------------------------------------------------
__global__ __launch_bounds__(512) void dense_kernel(
    const unsigned* __restrict__ packed, const int* __restrict__ cnt,
    const float* __restrict__ emb, const float* __restrict__ ln1g,
    const float* __restrict__ ln1b, const float* __restrict__ b1,
    const float* __restrict__ b2, const half8* __restrict__ wfrag,
    float* __restrict__ partial)
{
    const int tid = threadIdx.x;
    const int w  = tid >> 6;    // wave 0..7
    const int l  = tid & 63;
    const int ln = l & 15;
    const int lg = l >> 4;
    const int g32 = w * 4 + lg; // token slot 0..31

    __shared__ __align__(16) _Float16 x_lds[MTILE][EMBD + 8];   // 8.5 KB
    __shared__ __align__(16) _Float16 h1_lds[MTILE][H1 + 8];    // 16.5 KB
    __shared__ unsigned tok_lds[MTILE + 1];
    __shared__ __align__(16) float b1s[H1];                     // 1 KB
    __shared__ float b2s[H2];                                   // 0.5 KB

    // ---- param stash (before first barrier) ----
    if (tid < H1) b1s[tid] = b1[tid];
    else if (tid < H1 + H2) b2s[tid - H1] = b2[tid - H1];

    // ---- weight fragments in registers: 8-way N-split -> 64 VGPRs ----
    half8 w1r[4][2];
    #pragma unroll
    for (int kt = 0; kt < 4; ++kt)
      #pragma unroll
      for (int j = 0; j < 2; ++j)
        w1r[kt][j] = wfrag[(kt * 16 + w * 2 + j) * 64 + l];
    half8 w2r[8];
    #pragma unroll
    for (int kt = 0; kt < 8; ++kt)
        w2r[kt] = wfrag[4096 + (kt * 8 + w) * 64 + l];

    float g1r[8], b1r[8];
    #pragma unroll
    for (int i = 0; i < 8; ++i) { g1r[i] = ln1g[ln * 8 + i]; b1r[i] = ln1b[ln * 8 + i]; }

    const int total = *cnt;

    int tile = blockIdx.x;
    int base = tile * MTILE;

    // ---- prologue: prefetch tile0's pk/tok/emb ----
    unsigned pkA = 0xFFFFFFFFu, tokA = 0xFFFFFFFFu;
    float4 pa0, pa1; bool vA = false;
    if (base < total) {
        if (base + g32 < total) pkA = packed[base + g32];
        if (tid <= 32) {
            int ti = (tid < 32) ? base + tid : base - 1;
            tokA = (ti >= 0 && ti < total) ? packed[ti] : 0xFFFFFFFFu;
        }
        vA = (pkA != 0xFFFFFFFFu);
        if (vA) {
            const float4* src = (const float4*)(emb + (size_t)(pkA & 0x1FFFFu) * EMBD + ln * 8);
            pa0 = src[0]; pa1 = src[1];
        }
    }

    for (; base < total; tile += (int)gridDim.x, base = tile * MTILE) {
        const int nbase = (tile + (int)gridDim.x) * MTILE;

        // stage this tile's row tags
        if (tid <= 32) tok_lds[tid] = tokA;

        // issue next tile's pk/tok loads (stay in flight across barriers)
        unsigned pkN = 0xFFFFFFFFu, tokN = 0xFFFFFFFFu;
        if (nbase < total) {
            if (nbase + g32 < total) pkN = packed[nbase + g32];
            if (tid <= 32) {
                int ti = (tid < 32) ? nbase + tid : nbase - 1;
                tokN = (ti < total) ? packed[ti] : 0xFFFFFFFFu;
            }
        }

        // ---- LN1 of own token -> x_lds ----
        {
            half8 xo;
            if (vA) {
                float v[8] = {pa0.x, pa0.y, pa0.z, pa0.w, pa1.x, pa1.y, pa1.z, pa1.w};
                float sm = 0.f, ss = 0.f;
                #pragma unroll
                for (int k = 0; k < 8; ++k) { sm += v[k]; ss += v[k] * v[k]; }
                #pragma unroll
                for (int m = 1; m < 16; m <<= 1) {
                    sm += __shfl_xor(sm, m, 64);
                    ss += __shfl_xor(ss, m, 64);
                }
                float mu  = sm * (1.f / 128.f);
                float var = ss * (1.f / 128.f) - mu * mu;
                float rs  = rsqrtf(var + 1e-12f);
                #pragma unroll
                for (int k = 0; k < 8; ++k)
                    xo[k] = (_Float16)((v[k] - mu) * rs * g1r[k] + b1r[k]);
            } else {
                #pragma unroll
                for (int k = 0; k < 8; ++k) xo[k] = (_Float16)0.f;
            }
            *(half8*)&x_lds[g32][ln * 8] = xo;
        }

        BARRIER_LDS();   // x_lds + tok_lds (+ stash on first iter) ready

        // ---- GEMM1 (transposed): wave w -> H1 cols w*32..+31, reg weights ----
        f32x4 acc[2][2];
        acc[0][0] = (f32x4){0,0,0,0}; acc[0][1] = (f32x4){0,0,0,0};
        acc[1][0] = (f32x4){0,0,0,0}; acc[1][1] = (f32x4){0,0,0,0};
        #pragma unroll
        for (int kt = 0; kt < 4; ++kt) {
            half8 xf0 = *(const half8*)&x_lds[ln][kt * 32 + lg * 8];
            half8 xf1 = *(const half8*)&x_lds[16 + ln][kt * 32 + lg * 8];
            acc[0][0] = __builtin_amdgcn_mfma_f32_16x16x32_f16(w1r[kt][0], xf0, acc[0][0], 0, 0, 0);
            acc[0][1] = __builtin_amdgcn_mfma_f32_16x16x32_f16(w1r[kt][1], xf0, acc[0][1], 0, 0, 0);
            acc[1][0] = __builtin_amdgcn_mfma_f32_16x16x32_f16(w1r[kt][0], xf1, acc[1][0], 0, 0, 0);
            acc[1][1] = __builtin_amdgcn_mfma_f32_16x16x32_f16(w1r[kt][1], xf1, acc[1][1], 0, 0, 0);
        }

        // ---- issue next tile's emb gather (pkN has landed by now) ----
        float4 pb0, pb1; bool vN = (pkN != 0xFFFFFFFFu);
        if (vN) {
            const float4* src = (const float4*)(emb + (size_t)(pkN & 0x1FFFFu) * EMBD + ln * 8);
            pb0 = src[0]; pb1 = src[1];
        }

        // ---- GELU -> h1_lds (bias from LDS stash) ----
        #pragma unroll
        for (int m = 0; m < 2; ++m)
          #pragma unroll
          for (int j = 0; j < 2; ++j) {
            f32x4 bb = *(const f32x4*)&b1s[(w * 2 + j) * 16 + lg * 4];
            half4 hv;
            #pragma unroll
            for (int g2 = 0; g2 < 4; ++g2) {
                float h = acc[m][j][g2] + bb[g2];
                hv[g2] = (_Float16)gelu_exact(h);
            }
            *(half4*)&h1_lds[m * 16 + ln][(w * 2 + j) * 16 + lg * 4] = hv;
          }

        // ---- row tags -> regs + ballot segment mask (before bar2) ----
        int rowj = 0x7FFF, rowp = 0x7FFF;
        if (l < 32) {
            rowj = (int)(tok_lds[l] >> 17);
            rowp = (l == 0) ? (int)(tok_lds[32] >> 17) : (int)(tok_lds[l - 1] >> 17);
        }
        const int prevrow = (int)(tok_lds[32] >> 17);
        bool st = (l < 32) && ((l == 0) || (rowj != rowp));
        unsigned mask = (unsigned)__ballot(st);   // bits 0..31 = segment starts
        const float b2v = b2s[w * 16 + ln];

        BARRIER_LDS();   // h1_lds ready; tok_lds consumed

        // ---- GEMM2: wave w -> H2 cols w*16..+15, reg weights ----
        f32x4 acc2[2];
        acc2[0] = (f32x4){0,0,0,0}; acc2[1] = (f32x4){0,0,0,0};
        #pragma unroll
        for (int kt = 0; kt < 8; ++kt) {
            half8 a0 = *(const half8*)&h1_lds[ln][kt * 32 + lg * 8];
            half8 a1 = *(const half8*)&h1_lds[16 + ln][kt * 32 + lg * 8];
            acc2[0] = __builtin_amdgcn_mfma_f32_16x16x32_f16(a0, w2r[kt], acc2[0], 0, 0, 0);
            acc2[1] = __builtin_amdgcn_mfma_f32_16x16x32_f16(a1, w2r[kt], acc2[1], 0, 0, 0);
        }
        float val[2][4];
        #pragma unroll
        for (int m = 0; m < 2; ++m)
          #pragma unroll
          for (int g2 = 0; g2 < 4; ++g2)
            val[m][g2] = acc2[m][g2] + b2v;

        // ---- segmented max-pool (proven) ----
        {
            int s0 = 0;
            while (s0 < 32) {
                int s1;
                if (s0 >= 31) s1 = 32;
                else {
                    unsigned m2 = mask >> (s0 + 1);
                    s1 = m2 ? (s0 + __ffs(m2)) : 32;
                }
                int row = __shfl(rowj, s0, 64);
                if (row < NROWS) {
                    float mx = -INFINITY;
                    #pragma unroll
                    for (int m = 0; m < 2; ++m)
                      #pragma unroll
                      for (int g2 = 0; g2 < 4; ++g2) {
                        int tt = m * 16 + lg * 4 + g2;
                        if (tt >= s0 && tt < s1) mx = fmaxf(mx, val[m][g2]);
                      }
                    mx = fmaxf(mx, __shfl_xor(mx, 16, 64));
                    mx = fmaxf(mx, __shfl_xor(mx, 32, 64));
                    int side = (s0 == 0 && row == prevrow) ? 1 + (tile & 1) : 0;
                    if (l < 16)
                        partial[(size_t)row * 384 + side * 128 + w * 16 + l] = mx;
                }
                s0 = s1;
            }
        }

        // ---- rotate prefetch state ----
        pkA = pkN; tokA = tokN; vA = vN;
        if (vN) { pa0 = pb0; pa1 = pb1; }
    }
}

// ---------------------------------------------------------------------------
// K2: pool over VALID sides only (computed from rowstart/len; no -inf init
//     needed) -> LN2 -> fc.
//   Row occupies packed[start, start+len): first tile tf=start>>5, last
//   tl=(start+len-1)>>5. Side 0 written by tile tf; continuation tiles
//   tf+1, tf+2 (alternating parity, distinct) write sides 1+((tf+k)&1).
// ---------------------------------------------------------------------------
__global__ __launch_bounds__(256) void head_kernel(
    const float* __restrict__ partial, const int* __restrict__ rowstart,
    const int* __restrict__ lens, const float* __restrict__ ln2g,
    const float* __restrict__ ln2b, const float* __restrict__ fcw,
    const float* __restrict__ fcb, float* __restrict__ out)
{
    int w = threadIdx.x >> 6, l = threadIdx.x & 63;
    int r = blockIdx.x * 4 + w;
    const float* pr = partial + (size_t)r * 384;

    int start = rowstart[r];
    int len = lens[r]; len = len < 1 ? 1 : (len > SLEN ? SLEN : len);
    int tf = start >> 5, tl = (start + len - 1) >> 5;

    float v0 = pr[l], v1 = pr[64 + l];
    if (tl > tf) {
        int side = 1 + ((tf + 1) & 1);
        v0 = fmaxf(v0, pr[side * 128 + l]);
        v1 = fmaxf(v1, pr[side * 128 + 64 + l]);
    }
    if (tl > tf + 1) {
        int side = 1 + ((tf + 2) & 1);
        v0 = fmaxf(v0, pr[side * 128 + l]);
        v1 = fmaxf(v1, pr[side * 128 + 64 + l]);
    }

    float g2a = ln2g[l], g2c = ln2g[l + 64];
    float b2a = ln2b[l], b2c = ln2b[l + 64];
    float fwa = fcw[l],  fwc = fcw[l + 64];
    float s = v0 + v1, ss = v0 * v0 + v1 * v1;
    #pragma unroll
    for (int m = 1; m < 64; m <<= 1) {
        s  += __shfl_xor(s,  m, 64);
        ss += __shfl_xor(ss, m, 64);
    }
    float mu  = s * (1.f / 128.f);
    float var = ss * (1.f / 128.f) - mu * mu;
    float rs  = rsqrtf(var + 1e-12f);
    float n0 = (v0 - mu) * rs * g2a + b2a;
    float n1 = (v1 - mu) * rs * g2c + b2c;
    float dot = n0 * fwa + n1 * fwc;
    #pragma unroll
    for (int m = 1; m < 64; m <<= 1) dot += __shfl_xor(dot, m, 64);
    if (l == 0) out[r] = dot + fcb[0];
}

extern "C" void kernel_launch(void* const* d_in, const int* in_sizes, int n_in,
                              void* d_out, int out_size, void* d_ws, size_t ws_size,
                              hipStream_t stream) {
    const int*   ids  = (const int*)d_in[0];
    const int*   lens = (const int*)d_in[1];
    const float* emb  = (const float*)d_in[2];
    const float* ln1g = (const float*)d_in[3];
    const float* ln1b = (const float*)d_in[4];
    const float* w1   = (const float*)d_in[5];
    const float* b1   = (const float*)d_in[6];
    const float* w2   = (const float*)d_in[7];
    const float* b2   = (const float*)d_in[8];
    const float* ln2g = (const float*)d_in[9];
    const float* ln2b = (const float*)d_in[10];
    const float* fcw  = (const float*)d_in[11];
    const float* fcb  = (const float*)d_in[12];
    float* out = (float*)d_out;

    char* ws = (char*)d_ws;   // needs ~7.3 MB
    half8*    frags    = (half8*)(ws + WS_FRAGS);
    int*      cnt      = (int*)(ws + WS_CNT);
    int*      rowstart = (int*)(ws + WS_ROWSTART);
    unsigned* packed   = (unsigned*)(ws + WS_PACKED);
    float*    partial  = (float*)(ws + WS_PARTIAL);

    hipMemsetAsync(cnt, 0, sizeof(int), stream);
    hipLaunchKernelGGL(setup_kernel, dim3(528), dim3(512), 0, stream,
                       w1, w2, ids, lens, frags, packed, cnt, rowstart);
    hipLaunchKernelGGL(dense_kernel, dim3(DENSE_GRID), dim3(512), 0, stream,
                       packed, cnt, emb, ln1g, ln1b, b1, b2, frags, partial);
    hipLaunchKernelGGL(head_kernel, dim3(1024), dim3(256), 0, stream,
                       partial, rowstart, lens, ln2g, ln2b, fcw, fcb, out);
}

// Round 17
// 72.308 us; speedup vs baseline: 1.5672x; 1.5672x over previous
//
#include <hip/hip_runtime.h>
#include <hip/hip_bf16.h>
#include <math.h>

typedef __attribute__((ext_vector_type(8))) _Float16 half8;
typedef __attribute__((ext_vector_type(4))) _Float16 half4;
typedef __attribute__((ext_vector_type(4))) float f32x4;

#define EMBD 128
#define H1 256
#define H2 128
#define SLEN 50
#define NROWS 4096
#define MTILE 32
#define DENSE_GRID 512

// ---- d_ws layout (bytes) ----
#define WS_FRAGS    0          // half8 frags[8192]  (131072)
#define WS_CNT      131072     // int counter (pad to 131200)
#define WS_ROWSTART 131200     // int rowstart[4096] (16384) -> 147584
#define WS_PACKED   147584     // u32 packed[204800] (819200) -> 966784
#define WS_PARTIAL  966784     // float partial[4096][3][128] (6291456) — no init needed

// Branch-free GELU, exact-erf form via Abramowitz-Stegun 7.1.26 (|err|<=1.5e-7).
__device__ __forceinline__ float gelu_exact(float h) {
    float ah = fabsf(h);
    float d  = fmaf(0.23163845f, ah, 1.0f);
    float t;
    asm("v_rcp_f32 %0, %1" : "=v"(t) : "v"(d));
    float p = fmaf(1.061405429f, t, -1.453152027f);
    p = fmaf(p, t, 1.421413741f);
    p = fmaf(p, t, -0.284496736f);
    p = fmaf(p, t, 0.254829592f);
    p = p * t;
    float e;                                   // v_exp_f32 computes 2^x
    float x2 = h * h * -0.72134752f;           // -h^2/2 * log2(e)
    asm("v_exp_f32 %0, %1" : "=v"(e) : "v"(x2));
    float er = fmaf(-p, e, 1.0f);
    return fmaf(0.5f * ah, er, 0.5f * h);
}

// LDS-only barrier (no vmcnt drain): in-flight global loads survive it.
#define BARRIER_LDS() asm volatile("s_waitcnt lgkmcnt(0)\n\ts_barrier" ::: "memory")

// ---------------------------------------------------------------------------
// K0 (fused setup, 256 threads):
//   blocks 0..31  : w1/w2 fp32 -> fp16 MFMA fragments (8-wave layout, proven)
//   blocks 32..47 : compaction, R12-proven scan form — thread per row,
//                   wave-scan, ONE atomicAdd per wave (64 total).
//                   Also stores rowstart[r] for the head kernel.
// cnt zeroed beforehand via hipMemsetAsync.
// ---------------------------------------------------------------------------
__global__ __launch_bounds__(256) void setup_kernel(
    const float* __restrict__ w1, const float* __restrict__ w2,
    const int* __restrict__ ids, const int* __restrict__ lens,
    half8* __restrict__ frags, unsigned* __restrict__ packed,
    int* __restrict__ cnt, int* __restrict__ rowstart)
{
    int b = blockIdx.x, t = threadIdx.x;
    if (b < 32) {
        int f = b * 256 + t;   // 0..8191
        half8 v;
        if (f < 4096) {
            int fragid = f >> 6, lane = f & 63;
            int kt = fragid >> 4, nt = fragid & 15;
            int col = nt * 16 + (lane & 15);
            int kb  = kt * 32 + (lane >> 4) * 8;
            #pragma unroll
            for (int i = 0; i < 8; ++i) v[i] = (_Float16)w1[(size_t)(kb + i) * H1 + col];
            frags[f] = v;
        } else {
            int f2 = f - 4096;
            int fragid = f2 >> 6, lane = f2 & 63;
            int kt = fragid >> 3, ntc = fragid & 7;
            int col = ntc * 16 + (lane & 15);
            int kb  = kt * 32 + (lane >> 4) * 8;
            #pragma unroll
            for (int i = 0; i < 8; ++i) v[i] = (_Float16)w2[(size_t)(kb + i) * H2 + col];
            frags[4096 + f2] = v;
        }
    } else {
        // ---- compaction (R12/R15-proven): thread per row, 1 atomic per wave ----
        int gtid = (b - 32) * 256 + t;   // row 0..4095
        int lane = t & 63;
        int len = lens[gtid]; len = len < 1 ? 1 : (len > SLEN ? SLEN : len);
        int inc = len;
        #pragma unroll
        for (int off = 1; off < 64; off <<= 1) {
            int v = __shfl_up(inc, off, 64);
            if (lane >= off) inc += v;
        }
        int wave_total = __shfl(inc, 63, 64);
        int wbase;
        if (lane == 0) wbase = atomicAdd(cnt, wave_total);
        wbase = __shfl(wbase, 0, 64);
        int base = wbase + inc - len;
        rowstart[gtid] = base;
        unsigned rtag = (unsigned)gtid << 17;
        for (int k = 0; k < len; ++k)
            packed[base + k] = (unsigned)ids[gtid * SLEN + k] | rtag;
    }
}

// ---------------------------------------------------------------------------
// K1: dense 32-token tiles, 512 threads (8 waves). BYTE-IDENTICAL to the
//     proven R15 dense kernel (54.6us, absmax 0.015625). Weights in registers
//     at 8-way N-split; wave w: GEMM1 cols [w*32,+32), GEMM2 cols [w*16,+16).
// ---------------------------------------------------------------------------
__global__ __launch_bounds__(512) void dense_kernel(
    const unsigned* __restrict__ packed, const int* __restrict__ cnt,
    const float* __restrict__ emb, const float* __restrict__ ln1g,
    const float* __restrict__ ln1b, const float* __restrict__ b1,
    const float* __restrict__ b2, const half8* __restrict__ wfrag,
    float* __restrict__ partial)
{
    const int tid = threadIdx.x;
    const int w  = tid >> 6;    // wave 0..7
    const int l  = tid & 63;
    const int ln = l & 15;
    const int lg = l >> 4;
    const int g32 = w * 4 + lg; // token slot 0..31

    __shared__ __align__(16) _Float16 x_lds[MTILE][EMBD + 8];   // 8.5 KB
    __shared__ __align__(16) _Float16 h1_lds[MTILE][H1 + 8];    // 16.5 KB
    __shared__ unsigned tok_lds[MTILE + 1];
    __shared__ __align__(16) float b1s[H1];                     // 1 KB
    __shared__ float b2s[H2];                                   // 0.5 KB

    // ---- param stash (before first barrier) ----
    if (tid < H1) b1s[tid] = b1[tid];
    else if (tid < H1 + H2) b2s[tid - H1] = b2[tid - H1];

    // ---- weight fragments in registers: 8-way N-split -> 64 VGPRs ----
    half8 w1r[4][2];
    #pragma unroll
    for (int kt = 0; kt < 4; ++kt)
      #pragma unroll
      for (int j = 0; j < 2; ++j)
        w1r[kt][j] = wfrag[(kt * 16 + w * 2 + j) * 64 + l];
    half8 w2r[8];
    #pragma unroll
    for (int kt = 0; kt < 8; ++kt)
        w2r[kt] = wfrag[4096 + (kt * 8 + w) * 64 + l];

    float g1r[8], b1r[8];
    #pragma unroll
    for (int i = 0; i < 8; ++i) { g1r[i] = ln1g[ln * 8 + i]; b1r[i] = ln1b[ln * 8 + i]; }

    const int total = *cnt;

    int tile = blockIdx.x;
    int base = tile * MTILE;

    // ---- prologue: prefetch tile0's pk/tok/emb ----
    unsigned pkA = 0xFFFFFFFFu, tokA = 0xFFFFFFFFu;
    float4 pa0, pa1; bool vA = false;
    if (base < total) {
        if (base + g32 < total) pkA = packed[base + g32];
        if (tid <= 32) {
            int ti = (tid < 32) ? base + tid : base - 1;
            tokA = (ti >= 0 && ti < total) ? packed[ti] : 0xFFFFFFFFu;
        }
        vA = (pkA != 0xFFFFFFFFu);
        if (vA) {
            const float4* src = (const float4*)(emb + (size_t)(pkA & 0x1FFFFu) * EMBD + ln * 8);
            pa0 = src[0]; pa1 = src[1];
        }
    }

    for (; base < total; tile += (int)gridDim.x, base = tile * MTILE) {
        const int nbase = (tile + (int)gridDim.x) * MTILE;

        // stage this tile's row tags
        if (tid <= 32) tok_lds[tid] = tokA;

        // issue next tile's pk/tok loads (stay in flight across barriers)
        unsigned pkN = 0xFFFFFFFFu, tokN = 0xFFFFFFFFu;
        if (nbase < total) {
            if (nbase + g32 < total) pkN = packed[nbase + g32];
            if (tid <= 32) {
                int ti = (tid < 32) ? nbase + tid : nbase - 1;
                tokN = (ti < total) ? packed[ti] : 0xFFFFFFFFu;
            }
        }

        // ---- LN1 of own token -> x_lds ----
        {
            half8 xo;
            if (vA) {
                float v[8] = {pa0.x, pa0.y, pa0.z, pa0.w, pa1.x, pa1.y, pa1.z, pa1.w};
                float sm = 0.f, ss = 0.f;
                #pragma unroll
                for (int k = 0; k < 8; ++k) { sm += v[k]; ss += v[k] * v[k]; }
                #pragma unroll
                for (int m = 1; m < 16; m <<= 1) {
                    sm += __shfl_xor(sm, m, 64);
                    ss += __shfl_xor(ss, m, 64);
                }
                float mu  = sm * (1.f / 128.f);
                float var = ss * (1.f / 128.f) - mu * mu;
                float rs  = rsqrtf(var + 1e-12f);
                #pragma unroll
                for (int k = 0; k < 8; ++k)
                    xo[k] = (_Float16)((v[k] - mu) * rs * g1r[k] + b1r[k]);
            } else {
                #pragma unroll
                for (int k = 0; k < 8; ++k) xo[k] = (_Float16)0.f;
            }
            *(half8*)&x_lds[g32][ln * 8] = xo;
        }

        BARRIER_LDS();   // x_lds + tok_lds (+ stash on first iter) ready

        // ---- GEMM1 (transposed): wave w -> H1 cols w*32..+31, reg weights ----
        f32x4 acc[2][2];
        acc[0][0] = (f32x4){0,0,0,0}; acc[0][1] = (f32x4){0,0,0,0};
        acc[1][0] = (f32x4){0,0,0,0}; acc[1][1] = (f32x4){0,0,0,0};
        #pragma unroll
        for (int kt = 0; kt < 4; ++kt) {
            half8 xf0 = *(const half8*)&x_lds[ln][kt * 32 + lg * 8];
            half8 xf1 = *(const half8*)&x_lds[16 + ln][kt * 32 + lg * 8];
            acc[0][0] = __builtin_amdgcn_mfma_f32_16x16x32_f16(w1r[kt][0], xf0, acc[0][0], 0, 0, 0);
            acc[0][1] = __builtin_amdgcn_mfma_f32_16x16x32_f16(w1r[kt][1], xf0, acc[0][1], 0, 0, 0);
            acc[1][0] = __builtin_amdgcn_mfma_f32_16x16x32_f16(w1r[kt][0], xf1, acc[1][0], 0, 0, 0);
            acc[1][1] = __builtin_amdgcn_mfma_f32_16x16x32_f16(w1r[kt][1], xf1, acc[1][1], 0, 0, 0);
        }

        // ---- issue next tile's emb gather (pkN has landed by now) ----
        float4 pb0, pb1; bool vN = (pkN != 0xFFFFFFFFu);
        if (vN) {
            const float4* src = (const float4*)(emb + (size_t)(pkN & 0x1FFFFu) * EMBD + ln * 8);
            pb0 = src[0]; pb1 = src[1];
        }

        // ---- GELU -> h1_lds (bias from LDS stash) ----
        #pragma unroll
        for (int m = 0; m < 2; ++m)
          #pragma unroll
          for (int j = 0; j < 2; ++j) {
            f32x4 bb = *(const f32x4*)&b1s[(w * 2 + j) * 16 + lg * 4];
            half4 hv;
            #pragma unroll
            for (int g2 = 0; g2 < 4; ++g2) {
                float h = acc[m][j][g2] + bb[g2];
                hv[g2] = (_Float16)gelu_exact(h);
            }
            *(half4*)&h1_lds[m * 16 + ln][(w * 2 + j) * 16 + lg * 4] = hv;
          }

        // ---- row tags -> regs + ballot segment mask (before bar2) ----
        int rowj = 0x7FFF, rowp = 0x7FFF;
        if (l < 32) {
            rowj = (int)(tok_lds[l] >> 17);
            rowp = (l == 0) ? (int)(tok_lds[32] >> 17) : (int)(tok_lds[l - 1] >> 17);
        }
        const int prevrow = (int)(tok_lds[32] >> 17);
        bool st = (l < 32) && ((l == 0) || (rowj != rowp));
        unsigned mask = (unsigned)__ballot(st);   // bits 0..31 = segment starts
        const float b2v = b2s[w * 16 + ln];

        BARRIER_LDS();   // h1_lds ready; tok_lds consumed

        // ---- GEMM2: wave w -> H2 cols w*16..+15, reg weights ----
        f32x4 acc2[2];
        acc2[0] = (f32x4){0,0,0,0}; acc2[1] = (f32x4){0,0,0,0};
        #pragma unroll
        for (int kt = 0; kt < 8; ++kt) {
            half8 a0 = *(const half8*)&h1_lds[ln][kt * 32 + lg * 8];
            half8 a1 = *(const half8*)&h1_lds[16 + ln][kt * 32 + lg * 8];
            acc2[0] = __builtin_amdgcn_mfma_f32_16x16x32_f16(a0, w2r[kt], acc2[0], 0, 0, 0);
            acc2[1] = __builtin_amdgcn_mfma_f32_16x16x32_f16(a1, w2r[kt], acc2[1], 0, 0, 0);
        }
        float val[2][4];
        #pragma unroll
        for (int m = 0; m < 2; ++m)
          #pragma unroll
          for (int g2 = 0; g2 < 4; ++g2)
            val[m][g2] = acc2[m][g2] + b2v;

        // ---- segmented max-pool (proven) ----
        {
            int s0 = 0;
            while (s0 < 32) {
                int s1;
                if (s0 >= 31) s1 = 32;
                else {
                    unsigned m2 = mask >> (s0 + 1);
                    s1 = m2 ? (s0 + __ffs(m2)) : 32;
                }
                int row = __shfl(rowj, s0, 64);
                if (row < NROWS) {
                    float mx = -INFINITY;
                    #pragma unroll
                    for (int m = 0; m < 2; ++m)
                      #pragma unroll
                      for (int g2 = 0; g2 < 4; ++g2) {
                        int tt = m * 16 + lg * 4 + g2;
                        if (tt >= s0 && tt < s1) mx = fmaxf(mx, val[m][g2]);
                      }
                    mx = fmaxf(mx, __shfl_xor(mx, 16, 64));
                    mx = fmaxf(mx, __shfl_xor(mx, 32, 64));
                    int side = (s0 == 0 && row == prevrow) ? 1 + (tile & 1) : 0;
                    if (l < 16)
                        partial[(size_t)row * 384 + side * 128 + w * 16 + l] = mx;
                }
                s0 = s1;
            }
        }

        // ---- rotate prefetch state ----
        pkA = pkN; tokA = tokN; vA = vN;
        if (vN) { pa0 = pb0; pa1 = pb1; }
    }
}

// ---------------------------------------------------------------------------
// K2: pool over VALID sides only (from rowstart/len; no -inf init) -> LN2 -> fc.
//   Row occupies packed[start, start+len): tf=start>>5, tl=(start+len-1)>>5.
//   Side 0 written by tile tf; continuations tf+1, tf+2 (distinct parities)
//   write sides 1+((tf+k)&1).  (Validated in R16, absmax 0.015625.)
// ---------------------------------------------------------------------------
__global__ __launch_bounds__(256) void head_kernel(
    const float* __restrict__ partial, const int* __restrict__ rowstart,
    const int* __restrict__ lens, const float* __restrict__ ln2g,
    const float* __restrict__ ln2b, const float* __restrict__ fcw,
    const float* __restrict__ fcb, float* __restrict__ out)
{
    int w = threadIdx.x >> 6, l = threadIdx.x & 63;
    int r = blockIdx.x * 4 + w;
    const float* pr = partial + (size_t)r * 384;

    int start = rowstart[r];
    int len = lens[r]; len = len < 1 ? 1 : (len > SLEN ? SLEN : len);
    int tf = start >> 5, tl = (start + len - 1) >> 5;

    float v0 = pr[l], v1 = pr[64 + l];
    if (tl > tf) {
        int side = 1 + ((tf + 1) & 1);
        v0 = fmaxf(v0, pr[side * 128 + l]);
        v1 = fmaxf(v1, pr[side * 128 + 64 + l]);
    }
    if (tl > tf + 1) {
        int side = 1 + ((tf + 2) & 1);
        v0 = fmaxf(v0, pr[side * 128 + l]);
        v1 = fmaxf(v1, pr[side * 128 + 64 + l]);
    }

    float g2a = ln2g[l], g2c = ln2g[l + 64];
    float b2a = ln2b[l], b2c = ln2b[l + 64];
    float fwa = fcw[l],  fwc = fcw[l + 64];
    float s = v0 + v1, ss = v0 * v0 + v1 * v1;
    #pragma unroll
    for (int m = 1; m < 64; m <<= 1) {
        s  += __shfl_xor(s,  m, 64);
        ss += __shfl_xor(ss, m, 64);
    }
    float mu  = s * (1.f / 128.f);
    float var = ss * (1.f / 128.f) - mu * mu;
    float rs  = rsqrtf(var + 1e-12f);
    float n0 = (v0 - mu) * rs * g2a + b2a;
    float n1 = (v1 - mu) * rs * g2c + b2c;
    float dot = n0 * fwa + n1 * fwc;
    #pragma unroll
    for (int m = 1; m < 64; m <<= 1) dot += __shfl_xor(dot, m, 64);
    if (l == 0) out[r] = dot + fcb[0];
}

extern "C" void kernel_launch(void* const* d_in, const int* in_sizes, int n_in,
                              void* d_out, int out_size, void* d_ws, size_t ws_size,
                              hipStream_t stream) {
    const int*   ids  = (const int*)d_in[0];
    const int*   lens = (const int*)d_in[1];
    const float* emb  = (const float*)d_in[2];
    const float* ln1g = (const float*)d_in[3];
    const float* ln1b = (const float*)d_in[4];
    const float* w1   = (const float*)d_in[5];
    const float* b1   = (const float*)d_in[6];
    const float* w2   = (const float*)d_in[7];
    const float* b2   = (const float*)d_in[8];
    const float* ln2g = (const float*)d_in[9];
    const float* ln2b = (const float*)d_in[10];
    const float* fcw  = (const float*)d_in[11];
    const float* fcb  = (const float*)d_in[12];
    float* out = (float*)d_out;

    char* ws = (char*)d_ws;   // needs ~7.3 MB
    half8*    frags    = (half8*)(ws + WS_FRAGS);
    int*      cnt      = (int*)(ws + WS_CNT);
    int*      rowstart = (int*)(ws + WS_ROWSTART);
    unsigned* packed   = (unsigned*)(ws + WS_PACKED);
    float*    partial  = (float*)(ws + WS_PARTIAL);

    hipMemsetAsync(cnt, 0, sizeof(int), stream);
    hipLaunchKernelGGL(setup_kernel, dim3(48), dim3(256), 0, stream,
                       w1, w2, ids, lens, frags, packed, cnt, rowstart);
    hipLaunchKernelGGL(dense_kernel, dim3(DENSE_GRID), dim3(512), 0, stream,
                       packed, cnt, emb, ln1g, ln1b, b1, b2, frags, partial);
    hipLaunchKernelGGL(head_kernel, dim3(1024), dim3(256), 0, stream,
                       partial, rowstart, lens, ln2g, ln2b, fcw, fcb, out);
}

// Round 18
// 70.919 us; speedup vs baseline: 1.5978x; 1.0196x over previous
//
#include <hip/hip_runtime.h>
#include <hip/hip_bf16.h>
#include <math.h>

typedef __attribute__((ext_vector_type(8))) _Float16 half8;
typedef __attribute__((ext_vector_type(4))) _Float16 half4;
typedef __attribute__((ext_vector_type(4))) float f32x4;

#define EMBD 128
#define H1 256
#define H2 128
#define SLEN 50
#define NROWS 4096
#define MTILE 32
#define DENSE_GRID 768

// ---- d_ws layout (bytes) ----
#define WS_FRAGS    0          // half8 frags[8192]  (131072)
#define WS_ROWSTART 131072     // int rowstart[4096] (16384) -> 147456
#define WS_PACKED   147456     // u32 packed[204800] (819200) -> 966656
#define WS_PARTIAL  966656     // float partial[4096][3][128] (6291456) — no init needed

// Branch-free GELU, exact-erf form via Abramowitz-Stegun 7.1.26 (|err|<=1.5e-7).
__device__ __forceinline__ float gelu_exact(float h) {
    float ah = fabsf(h);
    float d  = fmaf(0.23163845f, ah, 1.0f);
    float t;
    asm("v_rcp_f32 %0, %1" : "=v"(t) : "v"(d));
    float p = fmaf(1.061405429f, t, -1.453152027f);
    p = fmaf(p, t, 1.421413741f);
    p = fmaf(p, t, -0.284496736f);
    p = fmaf(p, t, 0.254829592f);
    p = p * t;
    float e;                                   // v_exp_f32 computes 2^x
    float x2 = h * h * -0.72134752f;           // -h^2/2 * log2(e)
    asm("v_exp_f32 %0, %1" : "=v"(e) : "v"(x2));
    float er = fmaf(-p, e, 1.0f);
    return fmaf(0.5f * ah, er, 0.5f * h);
}

// LDS-only barrier (no vmcnt drain): in-flight global loads survive it.
#define BARRIER_LDS() asm volatile("s_waitcnt lgkmcnt(0)\n\ts_barrier" ::: "memory")

__device__ __forceinline__ int clamp_len(int v) {
    return v < 1 ? 1 : (v > SLEN ? SLEN : v);
}

// ---------------------------------------------------------------------------
// K0 (fused setup, 256 threads, NO atomics / NO memset needed):
//   blocks 0..31  : w1/w2 fp32 -> fp16 MFMA fragments (8-wave layout, proven)
//   blocks 32..47 : deterministic compaction — each wave owns 64 rows and
//                   redundantly computes base = sum(clamped lens[0..start))
//                   via coalesced chunks + wave reduce. Canonical row order.
// ---------------------------------------------------------------------------
__global__ __launch_bounds__(256) void setup_kernel(
    const float* __restrict__ w1, const float* __restrict__ w2,
    const int* __restrict__ ids, const int* __restrict__ lens,
    half8* __restrict__ frags, unsigned* __restrict__ packed,
    int* __restrict__ rowstart)
{
    int b = blockIdx.x, t = threadIdx.x;
    if (b < 32) {
        int f = b * 256 + t;   // 0..8191
        half8 v;
        if (f < 4096) {
            int fragid = f >> 6, lane = f & 63;
            int kt = fragid >> 4, nt = fragid & 15;
            int col = nt * 16 + (lane & 15);
            int kb  = kt * 32 + (lane >> 4) * 8;
            #pragma unroll
            for (int i = 0; i < 8; ++i) v[i] = (_Float16)w1[(size_t)(kb + i) * H1 + col];
            frags[f] = v;
        } else {
            int f2 = f - 4096;
            int fragid = f2 >> 6, lane = f2 & 63;
            int kt = fragid >> 3, ntc = fragid & 7;
            int col = ntc * 16 + (lane & 15);
            int kb  = kt * 32 + (lane >> 4) * 8;
            #pragma unroll
            for (int i = 0; i < 8; ++i) v[i] = (_Float16)w2[(size_t)(kb + i) * H2 + col];
            frags[4096 + f2] = v;
        }
    } else {
        // ---- deterministic compaction: wave owns rows [start_row, +64) ----
        int lane = t & 63;
        int wv   = t >> 6;                      // wave in block 0..3
        int start_row = ((b - 32) * 4 + wv) * 64;

        // base = sum of clamped lens[0..start_row), coalesced redundant scan
        int acc = 0;
        for (int j = lane; j < start_row; j += 64) acc += clamp_len(lens[j]);
        #pragma unroll
        for (int m = 1; m < 64; m <<= 1) acc += __shfl_xor(acc, m, 64);

        // intra-wave exclusive scan over this wave's 64 rows
        int r   = start_row + lane;
        int len = clamp_len(lens[r]);
        int inc = len;
        #pragma unroll
        for (int off = 1; off < 64; off <<= 1) {
            int v = __shfl_up(inc, off, 64);
            if (lane >= off) inc += v;
        }
        int base = acc + inc - len;
        rowstart[r] = base;
        unsigned rtag = (unsigned)r << 17;
        for (int k = 0; k < len; ++k)
            packed[base + k] = (unsigned)ids[r * SLEN + k] | rtag;
    }
}

// ---------------------------------------------------------------------------
// K1: dense 32-token tiles, 512 threads (8 waves). BYTE-IDENTICAL hot loop to
//     the proven R15/R17 dense kernel (54.6us, absmax 0.015625); only change:
//     total computed from rowstart+lens (uniform loads), grid 768 (3 blk/CU).
// ---------------------------------------------------------------------------
__global__ __launch_bounds__(512) void dense_kernel(
    const unsigned* __restrict__ packed, const int* __restrict__ rowstart,
    const int* __restrict__ lens,
    const float* __restrict__ emb, const float* __restrict__ ln1g,
    const float* __restrict__ ln1b, const float* __restrict__ b1,
    const float* __restrict__ b2, const half8* __restrict__ wfrag,
    float* __restrict__ partial)
{
    const int tid = threadIdx.x;
    const int w  = tid >> 6;    // wave 0..7
    const int l  = tid & 63;
    const int ln = l & 15;
    const int lg = l >> 4;
    const int g32 = w * 4 + lg; // token slot 0..31

    __shared__ __align__(16) _Float16 x_lds[MTILE][EMBD + 8];   // 8.5 KB
    __shared__ __align__(16) _Float16 h1_lds[MTILE][H1 + 8];    // 16.5 KB
    __shared__ unsigned tok_lds[MTILE + 1];
    __shared__ __align__(16) float b1s[H1];                     // 1 KB
    __shared__ float b2s[H2];                                   // 0.5 KB

    // ---- param stash (before first barrier) ----
    if (tid < H1) b1s[tid] = b1[tid];
    else if (tid < H1 + H2) b2s[tid - H1] = b2[tid - H1];

    // ---- weight fragments in registers: 8-way N-split -> 64 VGPRs ----
    half8 w1r[4][2];
    #pragma unroll
    for (int kt = 0; kt < 4; ++kt)
      #pragma unroll
      for (int j = 0; j < 2; ++j)
        w1r[kt][j] = wfrag[(kt * 16 + w * 2 + j) * 64 + l];
    half8 w2r[8];
    #pragma unroll
    for (int kt = 0; kt < 8; ++kt)
        w2r[kt] = wfrag[4096 + (kt * 8 + w) * 64 + l];

    float g1r[8], b1r[8];
    #pragma unroll
    for (int i = 0; i < 8; ++i) { g1r[i] = ln1g[ln * 8 + i]; b1r[i] = ln1b[ln * 8 + i]; }

    int lastLen = lens[NROWS - 1];
    lastLen = lastLen < 1 ? 1 : (lastLen > SLEN ? SLEN : lastLen);
    const int total = rowstart[NROWS - 1] + lastLen;

    int tile = blockIdx.x;
    int base = tile * MTILE;

    // ---- prologue: prefetch tile0's pk/tok/emb ----
    unsigned pkA = 0xFFFFFFFFu, tokA = 0xFFFFFFFFu;
    float4 pa0, pa1; bool vA = false;
    if (base < total) {
        if (base + g32 < total) pkA = packed[base + g32];
        if (tid <= 32) {
            int ti = (tid < 32) ? base + tid : base - 1;
            tokA = (ti >= 0 && ti < total) ? packed[ti] : 0xFFFFFFFFu;
        }
        vA = (pkA != 0xFFFFFFFFu);
        if (vA) {
            const float4* src = (const float4*)(emb + (size_t)(pkA & 0x1FFFFu) * EMBD + ln * 8);
            pa0 = src[0]; pa1 = src[1];
        }
    }

    for (; base < total; tile += (int)gridDim.x, base = tile * MTILE) {
        const int nbase = (tile + (int)gridDim.x) * MTILE;

        // stage this tile's row tags
        if (tid <= 32) tok_lds[tid] = tokA;

        // issue next tile's pk/tok loads (stay in flight across barriers)
        unsigned pkN = 0xFFFFFFFFu, tokN = 0xFFFFFFFFu;
        if (nbase < total) {
            if (nbase + g32 < total) pkN = packed[nbase + g32];
            if (tid <= 32) {
                int ti = (tid < 32) ? nbase + tid : nbase - 1;
                tokN = (ti < total) ? packed[ti] : 0xFFFFFFFFu;
            }
        }

        // ---- LN1 of own token -> x_lds ----
        {
            half8 xo;
            if (vA) {
                float v[8] = {pa0.x, pa0.y, pa0.z, pa0.w, pa1.x, pa1.y, pa1.z, pa1.w};
                float sm = 0.f, ss = 0.f;
                #pragma unroll
                for (int k = 0; k < 8; ++k) { sm += v[k]; ss += v[k] * v[k]; }
                #pragma unroll
                for (int m = 1; m < 16; m <<= 1) {
                    sm += __shfl_xor(sm, m, 64);
                    ss += __shfl_xor(ss, m, 64);
                }
                float mu  = sm * (1.f / 128.f);
                float var = ss * (1.f / 128.f) - mu * mu;
                float rs  = rsqrtf(var + 1e-12f);
                #pragma unroll
                for (int k = 0; k < 8; ++k)
                    xo[k] = (_Float16)((v[k] - mu) * rs * g1r[k] + b1r[k]);
            } else {
                #pragma unroll
                for (int k = 0; k < 8; ++k) xo[k] = (_Float16)0.f;
            }
            *(half8*)&x_lds[g32][ln * 8] = xo;
        }

        BARRIER_LDS();   // x_lds + tok_lds (+ stash on first iter) ready

        // ---- GEMM1 (transposed): wave w -> H1 cols w*32..+31, reg weights ----
        f32x4 acc[2][2];
        acc[0][0] = (f32x4){0,0,0,0}; acc[0][1] = (f32x4){0,0,0,0};
        acc[1][0] = (f32x4){0,0,0,0}; acc[1][1] = (f32x4){0,0,0,0};
        #pragma unroll
        for (int kt = 0; kt < 4; ++kt) {
            half8 xf0 = *(const half8*)&x_lds[ln][kt * 32 + lg * 8];
            half8 xf1 = *(const half8*)&x_lds[16 + ln][kt * 32 + lg * 8];
            acc[0][0] = __builtin_amdgcn_mfma_f32_16x16x32_f16(w1r[kt][0], xf0, acc[0][0], 0, 0, 0);
            acc[0][1] = __builtin_amdgcn_mfma_f32_16x16x32_f16(w1r[kt][1], xf0, acc[0][1], 0, 0, 0);
            acc[1][0] = __builtin_amdgcn_mfma_f32_16x16x32_f16(w1r[kt][0], xf1, acc[1][0], 0, 0, 0);
            acc[1][1] = __builtin_amdgcn_mfma_f32_16x16x32_f16(w1r[kt][1], xf1, acc[1][1], 0, 0, 0);
        }

        // ---- issue next tile's emb gather (pkN has landed by now) ----
        float4 pb0, pb1; bool vN = (pkN != 0xFFFFFFFFu);
        if (vN) {
            const float4* src = (const float4*)(emb + (size_t)(pkN & 0x1FFFFu) * EMBD + ln * 8);
            pb0 = src[0]; pb1 = src[1];
        }

        // ---- GELU -> h1_lds (bias from LDS stash) ----
        #pragma unroll
        for (int m = 0; m < 2; ++m)
          #pragma unroll
          for (int j = 0; j < 2; ++j) {
            f32x4 bb = *(const f32x4*)&b1s[(w * 2 + j) * 16 + lg * 4];
            half4 hv;
            #pragma unroll
            for (int g2 = 0; g2 < 4; ++g2) {
                float h = acc[m][j][g2] + bb[g2];
                hv[g2] = (_Float16)gelu_exact(h);
            }
            *(half4*)&h1_lds[m * 16 + ln][(w * 2 + j) * 16 + lg * 4] = hv;
          }

        // ---- row tags -> regs + ballot segment mask (before bar2) ----
        int rowj = 0x7FFF, rowp = 0x7FFF;
        if (l < 32) {
            rowj = (int)(tok_lds[l] >> 17);
            rowp = (l == 0) ? (int)(tok_lds[32] >> 17) : (int)(tok_lds[l - 1] >> 17);
        }
        const int prevrow = (int)(tok_lds[32] >> 17);
        bool st = (l < 32) && ((l == 0) || (rowj != rowp));
        unsigned mask = (unsigned)__ballot(st);   // bits 0..31 = segment starts
        const float b2v = b2s[w * 16 + ln];

        BARRIER_LDS();   // h1_lds ready; tok_lds consumed

        // ---- GEMM2: wave w -> H2 cols w*16..+15, reg weights ----
        f32x4 acc2[2];
        acc2[0] = (f32x4){0,0,0,0}; acc2[1] = (f32x4){0,0,0,0};
        #pragma unroll
        for (int kt = 0; kt < 8; ++kt) {
            half8 a0 = *(const half8*)&h1_lds[ln][kt * 32 + lg * 8];
            half8 a1 = *(const half8*)&h1_lds[16 + ln][kt * 32 + lg * 8];
            acc2[0] = __builtin_amdgcn_mfma_f32_16x16x32_f16(a0, w2r[kt], acc2[0], 0, 0, 0);
            acc2[1] = __builtin_amdgcn_mfma_f32_16x16x32_f16(a1, w2r[kt], acc2[1], 0, 0, 0);
        }
        float val[2][4];
        #pragma unroll
        for (int m = 0; m < 2; ++m)
          #pragma unroll
          for (int g2 = 0; g2 < 4; ++g2)
            val[m][g2] = acc2[m][g2] + b2v;

        // ---- segmented max-pool (proven) ----
        {
            int s0 = 0;
            while (s0 < 32) {
                int s1;
                if (s0 >= 31) s1 = 32;
                else {
                    unsigned m2 = mask >> (s0 + 1);
                    s1 = m2 ? (s0 + __ffs(m2)) : 32;
                }
                int row = __shfl(rowj, s0, 64);
                if (row < NROWS) {
                    float mx = -INFINITY;
                    #pragma unroll
                    for (int m = 0; m < 2; ++m)
                      #pragma unroll
                      for (int g2 = 0; g2 < 4; ++g2) {
                        int tt = m * 16 + lg * 4 + g2;
                        if (tt >= s0 && tt < s1) mx = fmaxf(mx, val[m][g2]);
                      }
                    mx = fmaxf(mx, __shfl_xor(mx, 16, 64));
                    mx = fmaxf(mx, __shfl_xor(mx, 32, 64));
                    int side = (s0 == 0 && row == prevrow) ? 1 + (tile & 1) : 0;
                    if (l < 16)
                        partial[(size_t)row * 384 + side * 128 + w * 16 + l] = mx;
                }
                s0 = s1;
            }
        }

        // ---- rotate prefetch state ----
        pkA = pkN; tokA = tokN; vA = vN;
        if (vN) { pa0 = pb0; pa1 = pb1; }
    }
}

// ---------------------------------------------------------------------------
// K2: pool over VALID sides only (from rowstart/len; no -inf init) -> LN2 -> fc.
//   Row occupies packed[start, start+len): tf=start>>5, tl=(start+len-1)>>5.
//   Side 0 written by tile tf; continuations tf+1, tf+2 (distinct parities)
//   write sides 1+((tf+k)&1).  (Validated R16/R17, absmax 0.015625.)
// ---------------------------------------------------------------------------
__global__ __launch_bounds__(256) void head_kernel(
    const float* __restrict__ partial, const int* __restrict__ rowstart,
    const int* __restrict__ lens, const float* __restrict__ ln2g,
    const float* __restrict__ ln2b, const float* __restrict__ fcw,
    const float* __restrict__ fcb, float* __restrict__ out)
{
    int w = threadIdx.x >> 6, l = threadIdx.x & 63;
    int r = blockIdx.x * 4 + w;
    const float* pr = partial + (size_t)r * 384;

    int start = rowstart[r];
    int len = lens[r]; len = len < 1 ? 1 : (len > SLEN ? SLEN : len);
    int tf = start >> 5, tl = (start + len - 1) >> 5;

    float v0 = pr[l], v1 = pr[64 + l];
    if (tl > tf) {
        int side = 1 + ((tf + 1) & 1);
        v0 = fmaxf(v0, pr[side * 128 + l]);
        v1 = fmaxf(v1, pr[side * 128 + 64 + l]);
    }
    if (tl > tf + 1) {
        int side = 1 + ((tf + 2) & 1);
        v0 = fmaxf(v0, pr[side * 128 + l]);
        v1 = fmaxf(v1, pr[side * 128 + 64 + l]);
    }

    float g2a = ln2g[l], g2c = ln2g[l + 64];
    float b2a = ln2b[l], b2c = ln2b[l + 64];
    float fwa = fcw[l],  fwc = fcw[l + 64];
    float s = v0 + v1, ss = v0 * v0 + v1 * v1;
    #pragma unroll
    for (int m = 1; m < 64; m <<= 1) {
        s  += __shfl_xor(s,  m, 64);
        ss += __shfl_xor(ss, m, 64);
    }
    float mu  = s * (1.f / 128.f);
    float var = ss * (1.f / 128.f) - mu * mu;
    float rs  = rsqrtf(var + 1e-12f);
    float n0 = (v0 - mu) * rs * g2a + b2a;
    float n1 = (v1 - mu) * rs * g2c + b2c;
    float dot = n0 * fwa + n1 * fwc;
    #pragma unroll
    for (int m = 1; m < 64; m <<= 1) dot += __shfl_xor(dot, m, 64);
    if (l == 0) out[r] = dot + fcb[0];
}

extern "C" void kernel_launch(void* const* d_in, const int* in_sizes, int n_in,
                              void* d_out, int out_size, void* d_ws, size_t ws_size,
                              hipStream_t stream) {
    const int*   ids  = (const int*)d_in[0];
    const int*   lens = (const int*)d_in[1];
    const float* emb  = (const float*)d_in[2];
    const float* ln1g = (const float*)d_in[3];
    const float* ln1b = (const float*)d_in[4];
    const float* w1   = (const float*)d_in[5];
    const float* b1   = (const float*)d_in[6];
    const float* w2   = (const float*)d_in[7];
    const float* b2   = (const float*)d_in[8];
    const float* ln2g = (const float*)d_in[9];
    const float* ln2b = (const float*)d_in[10];
    const float* fcw  = (const float*)d_in[11];
    const float* fcb  = (const float*)d_in[12];
    float* out = (float*)d_out;

    char* ws = (char*)d_ws;   // needs ~7.3 MB
    half8*    frags    = (half8*)(ws + WS_FRAGS);
    int*      rowstart = (int*)(ws + WS_ROWSTART);
    unsigned* packed   = (unsigned*)(ws + WS_PACKED);
    float*    partial  = (float*)(ws + WS_PARTIAL);

    hipLaunchKernelGGL(setup_kernel, dim3(48), dim3(256), 0, stream,
                       w1, w2, ids, lens, frags, packed, rowstart);
    hipLaunchKernelGGL(dense_kernel, dim3(DENSE_GRID), dim3(512), 0, stream,
                       packed, rowstart, lens, emb, ln1g, ln1b, b1, b2, frags, partial);
    hipLaunchKernelGGL(head_kernel, dim3(1024), dim3(256), 0, stream,
                       partial, rowstart, lens, ln2g, ln2b, fcw, fcb, out);
}